// Round 12
// baseline (347.865 us; speedup 1.0000x reference)
//
#include <hip/hip_runtime.h>

#define NN 50000
#define E0 200000
#define E2 400000
#define NGROUPS ((NN + 7) / 8)      // 6250
#define NCHUNK  ((NN + 255) / 256)  // 196
#define NTILES  ((NN + 63) / 64)    // 782

typedef __attribute__((ext_vector_type(8))) short short8;
typedef __attribute__((ext_vector_type(4))) float f32x4;

__device__ __forceinline__ float eluf(float x) { return x > 0.0f ? x : expm1f(x); }
__device__ __forceinline__ float sigmoidf(float x) { return 1.0f / (1.0f + expf(-x)); }
__device__ __forceinline__ unsigned rne_bf16(float x) {
    unsigned u = __float_as_uint(x);
    return (u + 0x7fffu + ((u >> 16) & 1u)) >> 16;
}

// ---------------- setup: spectral norm + zero cnt/fill/deg (1 dispatch)
__global__ __launch_bounds__(256) void k_setup(const float* __restrict__ Wl_in, const float* __restrict__ Wr_in,
                                               float* __restrict__ Wl_out, float* __restrict__ Wr_out,
                                               int* __restrict__ cnt, int* __restrict__ fill,
                                               float* __restrict__ deg) {
    __shared__ float W[32 * 33];
    __shared__ float us[32], vs[32], tmp[32];
    __shared__ float scal;
    int t = threadIdx.x;
    if (blockIdx.x < 2) {
        int l = blockIdx.x;
        for (int i = t; i < 1024; i += 256) W[(i >> 5) * 33 + (i & 31)] = Wr_in[l * 1024 + i];
        if (t < 32) us[t] = 0.17677669529663688f;
        __syncthreads();
        for (int it = 0; it < 20; ++it) {
            if (t < 32) { float a = 0; for (int r = 0; r < 32; ++r) a = fmaf(W[r * 33 + t], us[r], a); tmp[t] = a; }
            __syncthreads();
            if (t == 0) { float s = 0; for (int c = 0; c < 32; ++c) s += tmp[c] * tmp[c]; scal = 1.0f / (sqrtf(s) + 1e-12f); }
            __syncthreads();
            if (t < 32) vs[t] = tmp[t] * scal;
            __syncthreads();
            if (t < 32) { float a = 0; for (int c = 0; c < 32; ++c) a = fmaf(W[t * 33 + c], vs[c], a); tmp[t] = a; }
            __syncthreads();
            if (t == 0) { float s = 0; for (int r = 0; r < 32; ++r) s += tmp[r] * tmp[r]; scal = 1.0f / (sqrtf(s) + 1e-12f); }
            __syncthreads();
            if (t < 32) us[t] = tmp[t] * scal;
            __syncthreads();
        }
        if (t < 32) { float a = 0; for (int r = 0; r < 32; ++r) a = fmaf(W[r * 33 + t], us[r], a); tmp[t] = a; }
        __syncthreads();
        if (t == 0) {
            float s = 0; for (int c = 0; c < 32; ++c) s += tmp[c] * tmp[c];
            scal = (sqrtf(s) + 1e-12f) / s;   // 1/sigma
        }
        __syncthreads();
        for (int i = t; i < 1024; i += 256) Wr_out[l * 1024 + i] = W[(i >> 5) * 33 + (i & 31)] * scal;
        if (t == 0) {
            float M[9];
            for (int i = 0; i < 9; ++i) M[i] = Wl_in[l * 9 + i];
            float u[3] = {0.5773502691896258f, 0.5773502691896258f, 0.5773502691896258f};
            float v[3], u2[3];
            for (int it = 0; it < 20; ++it) {
                float s = 0;
                for (int c = 0; c < 3; ++c) { v[c] = M[c] * u[0] + M[3 + c] * u[1] + M[6 + c] * u[2]; s += v[c] * v[c]; }
                float inv = 1.0f / (sqrtf(s) + 1e-12f);
                for (int c = 0; c < 3; ++c) v[c] *= inv;
                s = 0;
                for (int r = 0; r < 3; ++r) { u2[r] = M[r * 3] * v[0] + M[r * 3 + 1] * v[1] + M[r * 3 + 2] * v[2]; s += u2[r] * u2[r]; }
                inv = 1.0f / (sqrtf(s) + 1e-12f);
                for (int r = 0; r < 3; ++r) u[r] = u2[r] * inv;
            }
            float s = 0;
            for (int c = 0; c < 3; ++c) { v[c] = M[c] * u[0] + M[3 + c] * u[1] + M[6 + c] * u[2]; s += v[c] * v[c]; }
            float inv = (sqrtf(s) + 1e-12f) / s;
            for (int i = 0; i < 9; ++i) Wl_out[l * 9 + i] = M[i] * inv;
        }
    } else {
        int base = (blockIdx.x - 2) * 256 + t;
        int stride = (gridDim.x - 2) * 256;
        for (int i = base; i < NN; i += stride) { cnt[i] = 0; fill[i] = 0; deg[i] = 0.0f; }
    }
}

// ---------------- MFMA GEMM: multi-tile grid-stride + N column-split (r11-proven)
template<int K, int N, int NH, bool ELU, bool HIST>
__global__ __launch_bounds__(256) void k_gemm(const float* __restrict__ X,
                                              const float* __restrict__ W,
                                              const float* __restrict__ bias,
                                              float* __restrict__ out,
                                              const int* __restrict__ row, int* __restrict__ cnt) {
    constexpr int KP = K + 8;
    constexpr int NT = NH / 16;
    constexpr int KS = K / 32;
    constexpr int NHALVES = N / NH;
    __shared__ __align__(16) unsigned short whi[NH * KP];
    __shared__ __align__(16) unsigned short wlo[NH * KP];
    int tid = threadIdx.x;
    if (HIST) {   // independent atomics issued first; latency hides behind GEMM
        for (int e = blockIdx.x * 256 + tid; e < E2; e += gridDim.x * 256)
            atomicAdd(&cnt[row[e]], 1);
    }
    const int ch = blockIdx.x % NHALVES;
    const int tstream = blockIdx.x / NHALVES;
    const int nstreams = gridDim.x / NHALVES;
    for (int i = tid; i < NH * K; i += 256) {     // stage once per block
        float v = W[ch * NH * K + i];
        int r = i / K, c = i % K;
        unsigned h = rne_bf16(v);
        whi[r * KP + c] = (unsigned short)h;
        wlo[r * KP + c] = (unsigned short)rne_bf16(v - __uint_as_float(h << 16));
    }
    __syncthreads();
    int wave = tid >> 6, lane = tid & 63;
    int quad = lane >> 4, r16 = lane & 15;
    for (int t = tstream; t < NTILES; t += nstreams) {
        long m = (long)t * 64 + wave * 16 + r16;
        long mc = m < NN ? m : (NN - 1);
        const float* xrow = X + mc * K + quad * 8;
        short8 ah[KS], al[KS];
#pragma unroll
        for (int ks = 0; ks < KS; ++ks) {
            const float4* xp = (const float4*)(xrow + ks * 32);
            float4 p0 = xp[0], p1 = xp[1];
            float xv[8] = {p0.x, p0.y, p0.z, p0.w, p1.x, p1.y, p1.z, p1.w};
#pragma unroll
            for (int j = 0; j < 8; ++j) {
                unsigned h = rne_bf16(xv[j]);
                ah[ks][j] = (short)h;
                al[ks][j] = (short)rne_bf16(xv[j] - __uint_as_float(h << 16));
            }
        }
        long mbase = (long)t * 64 + wave * 16 + quad * 4;
#pragma unroll
        for (int tt = 0; tt < NT; ++tt) {
            f32x4 acc = (f32x4){0.f, 0.f, 0.f, 0.f};
#pragma unroll
            for (int ks = 0; ks < KS; ++ks) {
                int ro = (tt * 16 + r16) * KP + ks * 32 + quad * 8;
                short8 bh = *(const short8*)&whi[ro];
                short8 bl = *(const short8*)&wlo[ro];
                acc = __builtin_amdgcn_mfma_f32_16x16x32_bf16(ah[ks], bh, acc, 0, 0, 0);
                acc = __builtin_amdgcn_mfma_f32_16x16x32_bf16(al[ks], bh, acc, 0, 0, 0);
                acc = __builtin_amdgcn_mfma_f32_16x16x32_bf16(ah[ks], bl, acc, 0, 0, 0);
            }
            // C/D layout: col = lane&15, row = quad*4 + reg [m89-verified]
            int coln = ch * NH + tt * 16 + r16;
            float b = bias[coln];
#pragma unroll
            for (int rr = 0; rr < 4; ++rr) {
                long mm = mbase + rr;
                if (mm < NN) {
                    float v = acc[rr] + b;
                    if (ELU) v = eluf(v);
                    out[mm * N + coln] = v;
                }
            }
        }
    }
}

// ---------------- CSR scans
__global__ __launch_bounds__(256) void k_scan1(const int* __restrict__ cnt, int* __restrict__ start,
                                               int* __restrict__ bsum) {
    __shared__ int s[256];
    int b = blockIdx.x, t = threadIdx.x;
    int i = b * 256 + t;
    int v = (i < NN) ? cnt[i] : 0;
    s[t] = v;
    __syncthreads();
    for (int off = 1; off < 256; off <<= 1) {
        int add = (t >= off) ? s[t - off] : 0;
        __syncthreads();
        s[t] += add;
        __syncthreads();
    }
    if (i < NN) start[i] = s[t] - v;
    if (t == 255) bsum[b] = s[t];
}
__global__ __launch_bounds__(256) void k_scan2(const int* __restrict__ bsum, int* __restrict__ bofs, int nb) {
    __shared__ int s[256];
    int t = threadIdx.x;
    int v = (t < nb) ? bsum[t] : 0;
    s[t] = v;
    __syncthreads();
    for (int off = 1; off < 256; off <<= 1) {
        int add = (t >= off) ? s[t - off] : 0;
        __syncthreads();
        s[t] += add;
        __syncthreads();
    }
    if (t < nb) bofs[t] = s[t] - v;
}
__global__ __launch_bounds__(256) void k_fill(const int* __restrict__ row, const int* __restrict__ start,
                                              const int* __restrict__ bofs,
                                              int* __restrict__ fill, int* __restrict__ eslot) {
    int e = blockIdx.x * 256 + threadIdx.x;
    if (e >= E2) return;
    int u = row[e];
    eslot[e] = start[u] + bofs[u >> 8] + atomicAdd(&fill[u], 1);
}

// ---------------- y (split-packed bf16: yA=y0|y1, yB=y2) + node projections; zeroes deg
__global__ __launch_bounds__(256) void k_y8(const float* __restrict__ xc,
                                            const float* __restrict__ Wl, const float* __restrict__ Wr,
                                            const float* __restrict__ Wsh, const float* __restrict__ Wwt,
                                            int layer, unsigned* __restrict__ yA,
                                            unsigned short* __restrict__ yB,
                                            float4* __restrict__ proj,
                                            float* __restrict__ deg) {
    __shared__ float wrs[32 * 33];
    __shared__ float wls[9];
    __shared__ float xcs[8][96];
    __shared__ float ws1[192], wt[192];
    int tid = threadIdx.x;
    int n0 = blockIdx.x * 8;
    if (tid < 8) { int nz = n0 + tid; if (nz < NN) deg[nz] = 0.0f; }
    for (int i = tid; i < 1024; i += 256) wrs[(i >> 5) * 33 + (i & 31)] = Wr[i];
    if (tid < 9) wls[tid] = Wl[tid];
    if (tid < 192) {
        ws1[tid] = Wsh[(layer * 3 + 1) * 192 + tid];  // only row 1 of W_sheaf survives Cayley (D=2)
        wt[tid]  = Wwt[layer * 192 + tid];
    }
    for (int i = tid; i < 768; i += 256) {
        int n = n0 + i / 96;
        xcs[i / 96][i % 96] = (n < NN) ? xc[n * 96 + i % 96] : 0.0f;
    }
    __syncthreads();
    int node = tid >> 5, c = tid & 31;
    int n = n0 + node;
    float a1 = 0, a2 = 0, a3 = 0, a4 = 0;
#pragma unroll
    for (int j = 0; j < 3; ++j) {
        int k = j * 32 + c;
        float xv = xcs[node][k];
        a1 = fmaf(xv, ws1[k], a1);
        a2 = fmaf(xv, ws1[96 + k], a2);
        a3 = fmaf(xv, wt[k], a3);
        a4 = fmaf(xv, wt[96 + k], a4);
    }
#pragma unroll
    for (int off = 16; off; off >>= 1) {
        a1 += __shfl_xor(a1, off);
        a2 += __shfl_xor(a2, off);
        a3 += __shfl_xor(a3, off);
        a4 += __shfl_xor(a4, off);
    }
    if (c == 0 && n < NN) proj[n] = make_float4(a1, a2, a3, a4);   // {aR, aC, wR, wC}
    if (n < NN) {
        float t0 = 0, t1 = 0, t2 = 0;
        const float* wr = &wrs[c * 33];
        const float* xr = xcs[node];
#pragma unroll
        for (int h = 0; h < 32; ++h) {
            float w = wr[h];
            t0 = fmaf(xr[h], w, t0);
            t1 = fmaf(xr[32 + h], w, t1);
            t2 = fmaf(xr[64 + h], w, t2);
        }
        float o0 = wls[0] * t0 + wls[1] * t1 + wls[2] * t2;
        float o1 = wls[3] * t0 + wls[4] * t1 + wls[5] * t2;
        float o2 = wls[6] * t0 + wls[7] * t1 + wls[8] * t2;
        yA[n * 32 + c] = rne_bf16(o0) | (rne_bf16(o1) << 16);
        yB[n * 32 + c] = (unsigned short)rne_bf16(o2);
    }
}

// ---------------- per-edge coefficients, 8B packed meta (E0 only; reverse via T^T) + degree
// meta.x = C_bf16 | S_bf16<<16 ; meta.y = v_u16 | w2_bf16<<16   (NN < 2^16)
__global__ __launch_bounds__(256) void k_coef(const int* __restrict__ row, const int* __restrict__ col,
                                              const int* __restrict__ eslot,
                                              const float4* __restrict__ proj,
                                              uint2* __restrict__ meta, float* __restrict__ deg) {
    int e = blockIdx.x * 256 + threadIdx.x;
    if (e >= E0) return;
    int u = row[e], v = col[e];
    float4 pu = proj[u], pv = proj[v];            // one 16B line per endpoint
    float a_e = tanhf(pu.x + pv.y);
    float a_r = tanhf(pv.x + pu.y);
    float wd_e = sigmoidf(pu.z + pv.w);
    float wd_r = sigmoidf(pv.z + pu.w);
    float w = wd_e * wd_r;
    float w2 = w * w;
    float ie = 1.0f / (1.0f + a_e * a_e), ir = 1.0f / (1.0f + a_r * a_r);
    float ce = (1.0f - a_e * a_e) * ie, se = 2.0f * a_e * ie;
    float cr = (1.0f - a_r * a_r) * ir, sr = 2.0f * a_r * ir;
    float C = ce * cr + se * sr;   // T_e = Q_e^T Q_rev ; T_rev = T_e^T -> (C,-S)
    float S = ce * sr - se * cr;
    unsigned cb = rne_bf16(C), sb = rne_bf16(S), wb = rne_bf16(w2);
    meta[eslot[e]]      = make_uint2(cb | (sb << 16), (unsigned)v | (wb << 16));
    meta[eslot[e + E0]] = make_uint2(cb | ((sb ^ 0x8000u) << 16), (unsigned)u | (wb << 16));
    atomicAdd(&deg[u], w2);
    atomicAdd(&deg[v], w2);
}

// ---------------- gather + residual update (8B meta, 3-line y rows, inline rsqrt)
__global__ __launch_bounds__(256) void k_gather(const int* __restrict__ start, const int* __restrict__ bofs,
                                                const int* __restrict__ cnt,
                                                const uint2* __restrict__ meta,
                                                const float* __restrict__ deg,
                                                const unsigned* __restrict__ yA,
                                                const unsigned short* __restrict__ yB,
                                                const float* __restrict__ eps,
                                                int layer, float* __restrict__ xc) {
    int tid = threadIdx.x;
    int node = tid >> 5, c = tid & 31;
    int n = blockIdx.x * 8 + node;
    if (n >= NN) return;
    int s0 = start[n] + bofs[n >> 8], ec = cnt[n];
    float dn = deg[n];
    float du = dn > 0.0f ? rsqrtf(fmaxf(dn, 1e-30f)) : 0.0f;
    float acc0 = 0, acc1 = 0, acc2 = 0;
    for (int bs = 0; bs < ec; bs += 32) {
        int nb2 = min(32, ec - bs);
        float CC = 0, SS = 0, cnl = 0;
        int vj = 0;
        if (c < nb2) {
            uint2 mt = meta[s0 + bs + c];
            vj = (int)(mt.y & 0xffffu);
            float w2 = __uint_as_float(mt.y & 0xffff0000u);
            float Cv = __uint_as_float(mt.x << 16);
            float Sv = __uint_as_float(mt.x & 0xffff0000u);
            float dv = deg[vj];
            float dvi = dv > 0.0f ? rsqrtf(fmaxf(dv, 1e-30f)) : 0.0f;
            cnl = w2 * du * dvi;
            CC = cnl * Cv;
            SS = cnl * Sv;
        }
        for (int j = 0; j < nb2; ++j) {
            float Cj = __shfl(CC, j, 32);
            float Sj = __shfl(SS, j, 32);
            float cj = __shfl(cnl, j, 32);
            int v = __shfl(vj, j, 32);
            unsigned ua = yA[v * 32 + c];
            unsigned ub = (unsigned)yB[v * 32 + c];
            float y0 = __uint_as_float(ua << 16);
            float y1 = __uint_as_float(ua & 0xffff0000u);
            float y2 = __uint_as_float(ub << 16);
            acc0 = fmaf(Cj, y0, acc0);
            acc0 = fmaf(-Sj, y1, acc0);
            acc1 = fmaf(Sj, y0, acc1);
            acc1 = fmaf(Cj, y1, acc1);
            acc2 = fmaf(cj, y2, acc2);
        }
    }
    float diag = dn > 0.0f ? 1.0f : 0.0f;
    unsigned ua = yA[n * 32 + c];
    unsigned ub = (unsigned)yB[n * 32 + c];
    float oy0 = __uint_as_float(ua << 16);
    float oy1 = __uint_as_float(ua & 0xffff0000u);
    float oy2 = __uint_as_float(ub << 16);
    float c0 = 1.0f + tanhf(eps[layer * 3 + 0]);
    float c1 = 1.0f + tanhf(eps[layer * 3 + 1]);
    float c2 = 1.0f + tanhf(eps[layer * 3 + 2]);
    int base = n * 96 + c;
    float z0 = eluf(diag * oy0 - acc0);
    float z1 = eluf(diag * oy1 - acc1);
    float z2 = eluf(diag * oy2 - acc2);
    xc[base]      = c0 * xc[base]      - z0;
    xc[base + 32] = c1 * xc[base + 32] - z1;
    xc[base + 64] = c2 * xc[base + 64] - z2;
}

extern "C" void kernel_launch(void* const* d_in, const int* in_sizes, int n_in,
                              void* d_out, int out_size, void* d_ws, size_t ws_size,
                              hipStream_t stream) {
    const float* x     = (const float*)d_in[0];
    const int*   ei    = (const int*)d_in[1];
    const float* W1    = (const float*)d_in[2];
    const float* b1    = (const float*)d_in[3];
    const float* W2    = (const float*)d_in[4];
    const float* b2    = (const float*)d_in[5];
    const float* Wl    = (const float*)d_in[6];
    const float* Wr    = (const float*)d_in[7];
    const float* eps   = (const float*)d_in[8];
    const float* Wsh   = (const float*)d_in[9];
    const float* Wwt   = (const float*)d_in[10];
    float* out = (float*)d_out;
    const int* row = ei;        // edge_index[0]
    const int* col = ei + E2;   // edge_index[1]

    char* pc = (char*)d_ws;
    float* xc    = (float*)pc;          pc += (size_t)NN * 96 * 4;
    uint2* meta  = (uint2*)pc;          pc += (size_t)E2 * 8;
    unsigned* yA = (unsigned*)pc;       pc += (size_t)NN * 32 * 4;
    unsigned short* yB = (unsigned short*)pc; pc += (size_t)NN * 32 * 2;
    pc = (char*)(((size_t)pc + 15) & ~(size_t)15);
    float4* proj = (float4*)pc;         pc += (size_t)NN * 16;
    float* deg   = (float*)pc;          pc += (size_t)NN * 4;
    float* Wl_n  = (float*)pc;          pc += 32 * 4;
    float* Wr_n  = (float*)pc;          pc += 2048 * 4;
    int* cnt     = (int*)pc;            pc += (size_t)NN * 4;
    int* start   = (int*)pc;            pc += (size_t)NN * 4;
    int* fill    = (int*)pc;            pc += (size_t)NN * 4;
    int* eslot   = (int*)pc;            pc += (size_t)E2 * 4;
    int* bsum    = (int*)pc;            pc += 256 * 4;
    int* bofs    = (int*)pc;            pc += 256 * 4;

    const int EB = (E2 + 255) / 256;

    // 12 dispatches total
    k_setup<<<34, 256, 0, stream>>>(Wl, Wr, Wl_n, Wr_n, cnt, fill, deg);
    k_gemm<128, 96, 48, true, true><<<512, 256, 0, stream>>>(x, W1, b1, xc, row, cnt);
    k_scan1<<<NCHUNK, 256, 0, stream>>>(cnt, start, bsum);
    k_scan2<<<1, 256, 0, stream>>>(bsum, bofs, NCHUNK);
    k_fill<<<EB, 256, 0, stream>>>(row, start, bofs, fill, eslot);
    for (int l = 0; l < 2; ++l) {
        k_y8<<<NGROUPS, 256, 0, stream>>>(xc, Wl_n + l * 9, Wr_n + l * 1024, Wsh, Wwt, l,
                                          yA, yB, proj, deg);
        k_coef<<<(E0 + 255) / 256, 256, 0, stream>>>(row, col, eslot, proj, meta, deg);
        k_gather<<<NGROUPS, 256, 0, stream>>>(start, bofs, cnt, meta, deg, yA, yB, eps, l, xc);
    }
    k_gemm<96, 32, 32, false, false><<<512, 256, 0, stream>>>(xc, W2, b2, out, nullptr, nullptr);
}

// Round 13
// 331.183 us; speedup vs baseline: 1.0504x; 1.0504x over previous
//
#include <hip/hip_runtime.h>

#define NN 50000
#define E0 200000
#define E2 400000
#define NGROUPS ((NN + 7) / 8)      // 6250 (×8 = 50000 exactly — no ragged tail)
#define NCHUNK  ((NN + 255) / 256)  // 196
#define NTILES  ((NN + 63) / 64)    // 782
#define EB      ((E2 + 255) / 256)  // 1563

typedef __attribute__((ext_vector_type(8))) short short8;
typedef __attribute__((ext_vector_type(4))) float f32x4;

__device__ __forceinline__ float eluf(float x) { return x > 0.0f ? x : expm1f(x); }
__device__ __forceinline__ float sigmoidf(float x) { return 1.0f / (1.0f + expf(-x)); }
__device__ __forceinline__ unsigned rne_bf16(float x) {
    unsigned u = __float_as_uint(x);
    return (u + 0x7fffu + ((u >> 16) & 1u)) >> 16;
}

// ---------------- setup: spectral norm + zero cnt/fill/deg0 (1 dispatch)
__global__ __launch_bounds__(256) void k_setup(const float* __restrict__ Wl_in, const float* __restrict__ Wr_in,
                                               float* __restrict__ Wl_out, float* __restrict__ Wr_out,
                                               int* __restrict__ cnt, int* __restrict__ fill,
                                               float* __restrict__ deg0) {
    __shared__ float W[32 * 33];
    __shared__ float us[32], vs[32], tmp[32];
    __shared__ float scal;
    int t = threadIdx.x;
    if (blockIdx.x < 2) {
        int l = blockIdx.x;
        for (int i = t; i < 1024; i += 256) W[(i >> 5) * 33 + (i & 31)] = Wr_in[l * 1024 + i];
        if (t < 32) us[t] = 0.17677669529663688f;
        __syncthreads();
        for (int it = 0; it < 20; ++it) {
            if (t < 32) { float a = 0; for (int r = 0; r < 32; ++r) a = fmaf(W[r * 33 + t], us[r], a); tmp[t] = a; }
            __syncthreads();
            if (t == 0) { float s = 0; for (int c = 0; c < 32; ++c) s += tmp[c] * tmp[c]; scal = 1.0f / (sqrtf(s) + 1e-12f); }
            __syncthreads();
            if (t < 32) vs[t] = tmp[t] * scal;
            __syncthreads();
            if (t < 32) { float a = 0; for (int c = 0; c < 32; ++c) a = fmaf(W[t * 33 + c], vs[c], a); tmp[t] = a; }
            __syncthreads();
            if (t == 0) { float s = 0; for (int r = 0; r < 32; ++r) s += tmp[r] * tmp[r]; scal = 1.0f / (sqrtf(s) + 1e-12f); }
            __syncthreads();
            if (t < 32) us[t] = tmp[t] * scal;
            __syncthreads();
        }
        if (t < 32) { float a = 0; for (int r = 0; r < 32; ++r) a = fmaf(W[r * 33 + t], us[r], a); tmp[t] = a; }
        __syncthreads();
        if (t == 0) {
            float s = 0; for (int c = 0; c < 32; ++c) s += tmp[c] * tmp[c];
            scal = (sqrtf(s) + 1e-12f) / s;   // 1/sigma
        }
        __syncthreads();
        for (int i = t; i < 1024; i += 256) Wr_out[l * 1024 + i] = W[(i >> 5) * 33 + (i & 31)] * scal;
        if (t == 0) {
            float M[9];
            for (int i = 0; i < 9; ++i) M[i] = Wl_in[l * 9 + i];
            float u[3] = {0.5773502691896258f, 0.5773502691896258f, 0.5773502691896258f};
            float v[3], u2[3];
            for (int it = 0; it < 20; ++it) {
                float s = 0;
                for (int c = 0; c < 3; ++c) { v[c] = M[c] * u[0] + M[3 + c] * u[1] + M[6 + c] * u[2]; s += v[c] * v[c]; }
                float inv = 1.0f / (sqrtf(s) + 1e-12f);
                for (int c = 0; c < 3; ++c) v[c] *= inv;
                s = 0;
                for (int r = 0; r < 3; ++r) { u2[r] = M[r * 3] * v[0] + M[r * 3 + 1] * v[1] + M[r * 3 + 2] * v[2]; s += u2[r] * u2[r]; }
                inv = 1.0f / (sqrtf(s) + 1e-12f);
                for (int r = 0; r < 3; ++r) u[r] = u2[r] * inv;
            }
            float s = 0;
            for (int c = 0; c < 3; ++c) { v[c] = M[c] * u[0] + M[3 + c] * u[1] + M[6 + c] * u[2]; s += v[c] * v[c]; }
            float inv = (sqrtf(s) + 1e-12f) / s;
            for (int i = 0; i < 9; ++i) Wl_out[l * 9 + i] = M[i] * inv;
        }
    } else {
        int base = (blockIdx.x - 2) * 256 + t;
        int stride = (gridDim.x - 2) * 256;
        for (int i = base; i < NN; i += stride) { cnt[i] = 0; fill[i] = 0; deg0[i] = 0.0f; }
    }
}

// ---------------- MFMA GEMM: multi-tile grid-stride + N column-split (r11-proven)
template<int K, int N, int NH, bool ELU, bool HIST>
__global__ __launch_bounds__(256) void k_gemm(const float* __restrict__ X,
                                              const float* __restrict__ W,
                                              const float* __restrict__ bias,
                                              float* __restrict__ out,
                                              const int* __restrict__ row, int* __restrict__ cnt) {
    constexpr int KP = K + 8;
    constexpr int NT = NH / 16;
    constexpr int KS = K / 32;
    constexpr int NHALVES = N / NH;
    __shared__ __align__(16) unsigned short whi[NH * KP];
    __shared__ __align__(16) unsigned short wlo[NH * KP];
    int tid = threadIdx.x;
    if (HIST) {   // independent atomics first; latency hides behind GEMM
        for (int e = blockIdx.x * 256 + tid; e < E2; e += gridDim.x * 256)
            atomicAdd(&cnt[row[e]], 1);
    }
    const int ch = blockIdx.x % NHALVES;
    const int tstream = blockIdx.x / NHALVES;
    const int nstreams = gridDim.x / NHALVES;
    for (int i = tid; i < NH * K; i += 256) {
        float v = W[ch * NH * K + i];
        int r = i / K, c = i % K;
        unsigned h = rne_bf16(v);
        whi[r * KP + c] = (unsigned short)h;
        wlo[r * KP + c] = (unsigned short)rne_bf16(v - __uint_as_float(h << 16));
    }
    __syncthreads();
    int wave = tid >> 6, lane = tid & 63;
    int quad = lane >> 4, r16 = lane & 15;
    for (int t = tstream; t < NTILES; t += nstreams) {
        long m = (long)t * 64 + wave * 16 + r16;
        long mc = m < NN ? m : (NN - 1);
        const float* xrow = X + mc * K + quad * 8;
        short8 ah[KS], al[KS];
#pragma unroll
        for (int ks = 0; ks < KS; ++ks) {
            const float4* xp = (const float4*)(xrow + ks * 32);
            float4 p0 = xp[0], p1 = xp[1];
            float xv[8] = {p0.x, p0.y, p0.z, p0.w, p1.x, p1.y, p1.z, p1.w};
#pragma unroll
            for (int j = 0; j < 8; ++j) {
                unsigned h = rne_bf16(xv[j]);
                ah[ks][j] = (short)h;
                al[ks][j] = (short)rne_bf16(xv[j] - __uint_as_float(h << 16));
            }
        }
        long mbase = (long)t * 64 + wave * 16 + quad * 4;
#pragma unroll
        for (int tt = 0; tt < NT; ++tt) {
            f32x4 acc = (f32x4){0.f, 0.f, 0.f, 0.f};
#pragma unroll
            for (int ks = 0; ks < KS; ++ks) {
                int ro = (tt * 16 + r16) * KP + ks * 32 + quad * 8;
                short8 bh = *(const short8*)&whi[ro];
                short8 bl = *(const short8*)&wlo[ro];
                acc = __builtin_amdgcn_mfma_f32_16x16x32_bf16(ah[ks], bh, acc, 0, 0, 0);
                acc = __builtin_amdgcn_mfma_f32_16x16x32_bf16(al[ks], bh, acc, 0, 0, 0);
                acc = __builtin_amdgcn_mfma_f32_16x16x32_bf16(ah[ks], bl, acc, 0, 0, 0);
            }
            // C/D layout: col = lane&15, row = quad*4 + reg [m89-verified]
            int coln = ch * NH + tt * 16 + r16;
            float b = bias[coln];
#pragma unroll
            for (int rr = 0; rr < 4; ++rr) {
                long mm = mbase + rr;
                if (mm < NN) {
                    float v = acc[rr] + b;
                    if (ELU) v = eluf(v);
                    out[mm * N + coln] = v;
                }
            }
        }
    }
}

// ---------------- CSR scans
__global__ __launch_bounds__(256) void k_scan1(const int* __restrict__ cnt, int* __restrict__ start,
                                               int* __restrict__ bsum) {
    __shared__ int s[256];
    int b = blockIdx.x, t = threadIdx.x;
    int i = b * 256 + t;
    int v = (i < NN) ? cnt[i] : 0;
    s[t] = v;
    __syncthreads();
    for (int off = 1; off < 256; off <<= 1) {
        int add = (t >= off) ? s[t - off] : 0;
        __syncthreads();
        s[t] += add;
        __syncthreads();
    }
    if (i < NN) start[i] = s[t] - v;
    if (t == 255) bsum[b] = s[t];
}
__global__ __launch_bounds__(256) void k_scan2(const int* __restrict__ bsum, int* __restrict__ bofs, int nb) {
    __shared__ int s[256];
    int t = threadIdx.x;
    int v = (t < nb) ? bsum[t] : 0;
    s[t] = v;
    __syncthreads();
    for (int off = 1; off < 256; off <<= 1) {
        int add = (t >= off) ? s[t - off] : 0;
        __syncthreads();
        s[t] += add;
        __syncthreads();
    }
    if (t < nb) bofs[t] = s[t] - v;
}

// ---------------- fused: blocks [0,NGROUPS) = y8 layer 0 ; [NGROUPS, +EB) = CSR fill
__global__ __launch_bounds__(256) void k_filly8(const float* __restrict__ xc,
                                                const float* __restrict__ Wl, const float* __restrict__ Wr,
                                                const float* __restrict__ Wsh, const float* __restrict__ Wwt,
                                                unsigned* __restrict__ yA, unsigned short* __restrict__ yB,
                                                float4* __restrict__ proj,
                                                const int* __restrict__ row, const int* __restrict__ start,
                                                const int* __restrict__ bofs,
                                                int* __restrict__ fill, int* __restrict__ eslot) {
    int tid = threadIdx.x;
    if (blockIdx.x >= NGROUPS) {   // CSR fill branch (no LDS use)
        int e = (blockIdx.x - NGROUPS) * 256 + tid;
        if (e < E2) {
            int u = row[e];
            eslot[e] = start[u] + bofs[u >> 8] + atomicAdd(&fill[u], 1);
        }
        return;
    }
    __shared__ float wrs[32 * 33];
    __shared__ float wls[9];
    __shared__ float xcs[8][96];
    __shared__ float ws1[192], wt[192];
    int n0 = blockIdx.x * 8;
    for (int i = tid; i < 1024; i += 256) wrs[(i >> 5) * 33 + (i & 31)] = Wr[i];
    if (tid < 9) wls[tid] = Wl[tid];
    if (tid < 192) {
        ws1[tid] = Wsh[192 + tid];   // layer 0, row 1 of W_sheaf (only row surviving Cayley, D=2)
        wt[tid]  = Wwt[tid];
    }
    for (int i = tid; i < 192; i += 256) {   // float4-vectorized xc staging: 8 nodes × 24 f4
        int nd = i / 24, of = (i % 24) * 4;
        *(float4*)&xcs[nd][of] = *(const float4*)&xc[(n0 + nd) * 96 + of];
    }
    __syncthreads();
    int node = tid >> 5, c = tid & 31;
    int n = n0 + node;
    float a1 = 0, a2 = 0, a3 = 0, a4 = 0;
#pragma unroll
    for (int j = 0; j < 3; ++j) {
        int k = j * 32 + c;
        float xv = xcs[node][k];
        a1 = fmaf(xv, ws1[k], a1);
        a2 = fmaf(xv, ws1[96 + k], a2);
        a3 = fmaf(xv, wt[k], a3);
        a4 = fmaf(xv, wt[96 + k], a4);
    }
#pragma unroll
    for (int off = 16; off; off >>= 1) {
        a1 += __shfl_xor(a1, off);
        a2 += __shfl_xor(a2, off);
        a3 += __shfl_xor(a3, off);
        a4 += __shfl_xor(a4, off);
    }
    if (c == 0) proj[n] = make_float4(a1, a2, a3, a4);   // {aR, aC, wR, wC}
    {
        float t0 = 0, t1 = 0, t2 = 0;
        const float* wr = &wrs[c * 33];
        const float* xr = xcs[node];
#pragma unroll
        for (int h = 0; h < 32; ++h) {
            float w = wr[h];
            t0 = fmaf(xr[h], w, t0);
            t1 = fmaf(xr[32 + h], w, t1);
            t2 = fmaf(xr[64 + h], w, t2);
        }
        float o0 = wls[0] * t0 + wls[1] * t1 + wls[2] * t2;
        float o1 = wls[3] * t0 + wls[4] * t1 + wls[5] * t2;
        float o2 = wls[6] * t0 + wls[7] * t1 + wls[8] * t2;
        yA[n * 32 + c] = rne_bf16(o0) | (rne_bf16(o1) << 16);
        yB[n * 32 + c] = (unsigned short)rne_bf16(o2);
    }
}

// ---------------- per-edge coefficients, 8B packed meta + degree (ping-pong deg)
__global__ __launch_bounds__(256) void k_coef(const int* __restrict__ row, const int* __restrict__ col,
                                              const int* __restrict__ eslot,
                                              const float4* __restrict__ proj,
                                              uint2* __restrict__ meta, float* __restrict__ deg) {
    int e = blockIdx.x * 256 + threadIdx.x;
    if (e >= E0) return;
    int u = row[e], v = col[e];
    float4 pu = proj[u], pv = proj[v];
    float a_e = tanhf(pu.x + pv.y);
    float a_r = tanhf(pv.x + pu.y);
    float wd_e = sigmoidf(pu.z + pv.w);
    float wd_r = sigmoidf(pv.z + pu.w);
    float w = wd_e * wd_r;
    float w2 = w * w;
    float ie = 1.0f / (1.0f + a_e * a_e), ir = 1.0f / (1.0f + a_r * a_r);
    float ce = (1.0f - a_e * a_e) * ie, se = 2.0f * a_e * ie;
    float cr = (1.0f - a_r * a_r) * ir, sr = 2.0f * a_r * ir;
    float C = ce * cr + se * sr;   // T_e = Q_e^T Q_rev ; T_rev = T_e^T -> (C,-S)
    float S = ce * sr - se * cr;
    unsigned cb = rne_bf16(C), sb = rne_bf16(S), wb = rne_bf16(w2);
    meta[eslot[e]]      = make_uint2(cb | (sb << 16), (unsigned)v | (wb << 16));
    meta[eslot[e + E0]] = make_uint2(cb | ((sb ^ 0x8000u) << 16), (unsigned)u | (wb << 16));
    atomicAdd(&deg[u], w2);
    atomicAdd(&deg[v], w2);
}

// ---------------- gather layer 0 + residual + FUSED y8 layer 1 (ping-pong y/deg)
__global__ __launch_bounds__(256) void k_gatherY(const int* __restrict__ start, const int* __restrict__ bofs,
                                                 const int* __restrict__ cnt,
                                                 const uint2* __restrict__ meta,
                                                 const float* __restrict__ deg0,
                                                 const unsigned* __restrict__ yA0,
                                                 const unsigned short* __restrict__ yB0,
                                                 const float* __restrict__ eps,
                                                 float* __restrict__ xc,
                                                 const float* __restrict__ Wl, const float* __restrict__ Wr,
                                                 const float* __restrict__ Wsh, const float* __restrict__ Wwt,
                                                 unsigned* __restrict__ yA1, unsigned short* __restrict__ yB1,
                                                 float4* __restrict__ proj, float* __restrict__ deg1) {
    __shared__ float wrs[32 * 33];
    __shared__ float wls[9];
    __shared__ float xcs[8][96];
    __shared__ float ws1[192], wt[192];
    int tid = threadIdx.x;
    for (int i = tid; i < 1024; i += 256) wrs[(i >> 5) * 33 + (i & 31)] = Wr[i];
    if (tid < 9) wls[tid] = Wl[tid];
    if (tid < 192) {
        ws1[tid] = Wsh[(1 * 3 + 1) * 192 + tid];   // layer 1 sheaf row
        wt[tid]  = Wwt[1 * 192 + tid];
    }
    int node = tid >> 5, c = tid & 31;
    int n = blockIdx.x * 8 + node;                 // NGROUPS*8 == NN: always in range
    int s0 = start[n] + bofs[n >> 8], ec = cnt[n];
    float dn = deg0[n];
    float du = dn > 0.0f ? rsqrtf(fmaxf(dn, 1e-30f)) : 0.0f;
    float acc0 = 0, acc1 = 0, acc2 = 0;
    for (int bs = 0; bs < ec; bs += 32) {
        int nb2 = min(32, ec - bs);
        float CC = 0, SS = 0, cnl = 0;
        int vj = 0;
        if (c < nb2) {
            uint2 mt = meta[s0 + bs + c];
            vj = (int)(mt.y & 0xffffu);
            float w2 = __uint_as_float(mt.y & 0xffff0000u);
            float Cv = __uint_as_float(mt.x << 16);
            float Sv = __uint_as_float(mt.x & 0xffff0000u);
            float dv = deg0[vj];
            float dvi = dv > 0.0f ? rsqrtf(fmaxf(dv, 1e-30f)) : 0.0f;
            cnl = w2 * du * dvi;
            CC = cnl * Cv;
            SS = cnl * Sv;
        }
        for (int j = 0; j < nb2; ++j) {
            float Cj = __shfl(CC, j, 32);
            float Sj = __shfl(SS, j, 32);
            float cj = __shfl(cnl, j, 32);
            int v = __shfl(vj, j, 32);
            unsigned ua = yA0[v * 32 + c];
            unsigned ub = (unsigned)yB0[v * 32 + c];
            float y0 = __uint_as_float(ua << 16);
            float y1 = __uint_as_float(ua & 0xffff0000u);
            float y2 = __uint_as_float(ub << 16);
            acc0 = fmaf(Cj, y0, acc0);
            acc0 = fmaf(-Sj, y1, acc0);
            acc1 = fmaf(Sj, y0, acc1);
            acc1 = fmaf(Cj, y1, acc1);
            acc2 = fmaf(cj, y2, acc2);
        }
    }
    float diag = dn > 0.0f ? 1.0f : 0.0f;
    unsigned ua = yA0[n * 32 + c];
    unsigned ub = (unsigned)yB0[n * 32 + c];
    float oy0 = __uint_as_float(ua << 16);
    float oy1 = __uint_as_float(ua & 0xffff0000u);
    float oy2 = __uint_as_float(ub << 16);
    float c0 = 1.0f + tanhf(eps[0]);
    float c1 = 1.0f + tanhf(eps[1]);
    float c2 = 1.0f + tanhf(eps[2]);
    int base = n * 96 + c;
    float nx0 = c0 * xc[base]      - eluf(diag * oy0 - acc0);
    float nx1 = c1 * xc[base + 32] - eluf(diag * oy1 - acc1);
    float nx2 = c2 * xc[base + 64] - eluf(diag * oy2 - acc2);
    xc[base] = nx0; xc[base + 32] = nx1; xc[base + 64] = nx2;
    if (c == 0) deg1[n] = 0.0f;                    // zero next layer's degree
    xcs[node][c] = nx0; xcs[node][32 + c] = nx1; xcs[node][64 + c] = nx2;
    __syncthreads();
    // ---- layer-1 projections (own channels are in registers) ----
    float a1 = nx0 * ws1[c] + nx1 * ws1[32 + c] + nx2 * ws1[64 + c];
    float a2 = nx0 * ws1[96 + c] + nx1 * ws1[128 + c] + nx2 * ws1[160 + c];
    float a3 = nx0 * wt[c] + nx1 * wt[32 + c] + nx2 * wt[64 + c];
    float a4 = nx0 * wt[96 + c] + nx1 * wt[128 + c] + nx2 * wt[160 + c];
#pragma unroll
    for (int off = 16; off; off >>= 1) {
        a1 += __shfl_xor(a1, off);
        a2 += __shfl_xor(a2, off);
        a3 += __shfl_xor(a3, off);
        a4 += __shfl_xor(a4, off);
    }
    if (c == 0) proj[n] = make_float4(a1, a2, a3, a4);
    // ---- layer-1 y ----
    {
        float t0 = 0, t1 = 0, t2 = 0;
        const float* wr = &wrs[c * 33];
        const float* xr = xcs[node];
#pragma unroll
        for (int h = 0; h < 32; ++h) {
            float w = wr[h];
            t0 = fmaf(xr[h], w, t0);
            t1 = fmaf(xr[32 + h], w, t1);
            t2 = fmaf(xr[64 + h], w, t2);
        }
        float o0 = wls[0] * t0 + wls[1] * t1 + wls[2] * t2;
        float o1 = wls[3] * t0 + wls[4] * t1 + wls[5] * t2;
        float o2 = wls[6] * t0 + wls[7] * t1 + wls[8] * t2;
        yA1[n * 32 + c] = rne_bf16(o0) | (rne_bf16(o1) << 16);
        yB1[n * 32 + c] = (unsigned short)rne_bf16(o2);
    }
}

// ---------------- plain gather + residual (layer 1)
__global__ __launch_bounds__(256) void k_gather(const int* __restrict__ start, const int* __restrict__ bofs,
                                                const int* __restrict__ cnt,
                                                const uint2* __restrict__ meta,
                                                const float* __restrict__ deg,
                                                const unsigned* __restrict__ yA,
                                                const unsigned short* __restrict__ yB,
                                                const float* __restrict__ eps,
                                                int layer, float* __restrict__ xc) {
    int tid = threadIdx.x;
    int node = tid >> 5, c = tid & 31;
    int n = blockIdx.x * 8 + node;
    if (n >= NN) return;
    int s0 = start[n] + bofs[n >> 8], ec = cnt[n];
    float dn = deg[n];
    float du = dn > 0.0f ? rsqrtf(fmaxf(dn, 1e-30f)) : 0.0f;
    float acc0 = 0, acc1 = 0, acc2 = 0;
    for (int bs = 0; bs < ec; bs += 32) {
        int nb2 = min(32, ec - bs);
        float CC = 0, SS = 0, cnl = 0;
        int vj = 0;
        if (c < nb2) {
            uint2 mt = meta[s0 + bs + c];
            vj = (int)(mt.y & 0xffffu);
            float w2 = __uint_as_float(mt.y & 0xffff0000u);
            float Cv = __uint_as_float(mt.x << 16);
            float Sv = __uint_as_float(mt.x & 0xffff0000u);
            float dv = deg[vj];
            float dvi = dv > 0.0f ? rsqrtf(fmaxf(dv, 1e-30f)) : 0.0f;
            cnl = w2 * du * dvi;
            CC = cnl * Cv;
            SS = cnl * Sv;
        }
        for (int j = 0; j < nb2; ++j) {
            float Cj = __shfl(CC, j, 32);
            float Sj = __shfl(SS, j, 32);
            float cj = __shfl(cnl, j, 32);
            int v = __shfl(vj, j, 32);
            unsigned ua = yA[v * 32 + c];
            unsigned ub = (unsigned)yB[v * 32 + c];
            float y0 = __uint_as_float(ua << 16);
            float y1 = __uint_as_float(ua & 0xffff0000u);
            float y2 = __uint_as_float(ub << 16);
            acc0 = fmaf(Cj, y0, acc0);
            acc0 = fmaf(-Sj, y1, acc0);
            acc1 = fmaf(Sj, y0, acc1);
            acc1 = fmaf(Cj, y1, acc1);
            acc2 = fmaf(cj, y2, acc2);
        }
    }
    float diag = dn > 0.0f ? 1.0f : 0.0f;
    unsigned ua = yA[n * 32 + c];
    unsigned ub = (unsigned)yB[n * 32 + c];
    float oy0 = __uint_as_float(ua << 16);
    float oy1 = __uint_as_float(ua & 0xffff0000u);
    float oy2 = __uint_as_float(ub << 16);
    float c0 = 1.0f + tanhf(eps[layer * 3 + 0]);
    float c1 = 1.0f + tanhf(eps[layer * 3 + 1]);
    float c2 = 1.0f + tanhf(eps[layer * 3 + 2]);
    int base = n * 96 + c;
    float z0 = eluf(diag * oy0 - acc0);
    float z1 = eluf(diag * oy1 - acc1);
    float z2 = eluf(diag * oy2 - acc2);
    xc[base]      = c0 * xc[base]      - z0;
    xc[base + 32] = c1 * xc[base + 32] - z1;
    xc[base + 64] = c2 * xc[base + 64] - z2;
}

extern "C" void kernel_launch(void* const* d_in, const int* in_sizes, int n_in,
                              void* d_out, int out_size, void* d_ws, size_t ws_size,
                              hipStream_t stream) {
    const float* x     = (const float*)d_in[0];
    const int*   ei    = (const int*)d_in[1];
    const float* W1    = (const float*)d_in[2];
    const float* b1    = (const float*)d_in[3];
    const float* W2    = (const float*)d_in[4];
    const float* b2    = (const float*)d_in[5];
    const float* Wl    = (const float*)d_in[6];
    const float* Wr    = (const float*)d_in[7];
    const float* eps   = (const float*)d_in[8];
    const float* Wsh   = (const float*)d_in[9];
    const float* Wwt   = (const float*)d_in[10];
    float* out = (float*)d_out;
    const int* row = ei;        // edge_index[0]
    const int* col = ei + E2;   // edge_index[1]

    char* pc = (char*)d_ws;
    float* xc     = (float*)pc;          pc += (size_t)NN * 96 * 4;
    uint2* meta   = (uint2*)pc;          pc += (size_t)E2 * 8;
    unsigned* yA0 = (unsigned*)pc;       pc += (size_t)NN * 32 * 4;
    unsigned* yA1 = (unsigned*)pc;       pc += (size_t)NN * 32 * 4;
    unsigned short* yB0 = (unsigned short*)pc; pc += (size_t)NN * 32 * 2;
    unsigned short* yB1 = (unsigned short*)pc; pc += (size_t)NN * 32 * 2;
    pc = (char*)(((size_t)pc + 15) & ~(size_t)15);
    float4* proj  = (float4*)pc;         pc += (size_t)NN * 16;
    float* deg0   = (float*)pc;          pc += (size_t)NN * 4;
    float* deg1   = (float*)pc;          pc += (size_t)NN * 4;
    float* Wl_n   = (float*)pc;          pc += 32 * 4;
    float* Wr_n   = (float*)pc;          pc += 2048 * 4;
    int* cnt      = (int*)pc;            pc += (size_t)NN * 4;
    int* start    = (int*)pc;            pc += (size_t)NN * 4;
    int* fill     = (int*)pc;            pc += (size_t)NN * 4;
    int* eslot    = (int*)pc;            pc += (size_t)E2 * 4;
    int* bsum     = (int*)pc;            pc += 256 * 4;
    int* bofs     = (int*)pc;            pc += 256 * 4;

    // 10 dispatches total
    k_setup<<<34, 256, 0, stream>>>(Wl, Wr, Wl_n, Wr_n, cnt, fill, deg0);
    k_gemm<128, 96, 48, true, true><<<512, 256, 0, stream>>>(x, W1, b1, xc, row, cnt);
    k_scan1<<<NCHUNK, 256, 0, stream>>>(cnt, start, bsum);
    k_scan2<<<1, 256, 0, stream>>>(bsum, bofs, NCHUNK);
    k_filly8<<<NGROUPS + EB, 256, 0, stream>>>(xc, Wl_n, Wr_n, Wsh, Wwt,
                                               yA0, yB0, proj, row, start, bofs, fill, eslot);
    k_coef<<<(E0 + 255) / 256, 256, 0, stream>>>(row, col, eslot, proj, meta, deg0);
    k_gatherY<<<NGROUPS, 256, 0, stream>>>(start, bofs, cnt, meta, deg0, yA0, yB0, eps, xc,
                                           Wl_n + 9, Wr_n + 1024, Wsh, Wwt, yA1, yB1, proj, deg1);
    k_coef<<<(E0 + 255) / 256, 256, 0, stream>>>(row, col, eslot, proj, meta, deg1);
    k_gather<<<NGROUPS, 256, 0, stream>>>(start, bofs, cnt, meta, deg1, yA1, yB1, eps, 1, xc);
    k_gemm<96, 32, 32, false, false><<<512, 256, 0, stream>>>(xc, W2, b2, out, nullptr, nullptr);
}

// Round 14
// 322.219 us; speedup vs baseline: 1.0796x; 1.0278x over previous
//
#include <hip/hip_runtime.h>

#define NN 50000
#define E0 200000
#define E2 400000
#define NGROUPS ((NN + 7) / 8)      // 6250 (×8 = 50000 exactly)
#define NCHUNK  ((NN + 255) / 256)  // 196
#define NTILES  ((NN + 63) / 64)    // 782
#define EB      ((E2 + 255) / 256)  // 1563

typedef __attribute__((ext_vector_type(8))) short short8;
typedef __attribute__((ext_vector_type(4))) float f32x4;

__device__ __forceinline__ float eluf(float x) { return x > 0.0f ? x : expm1f(x); }
__device__ __forceinline__ float fsig(float x) { return 1.0f / (1.0f + __expf(-x)); }
__device__ __forceinline__ float ftanh(float x) {
    float e = __expf(-2.0f * x);
    return (1.0f - e) / (1.0f + e);
}
__device__ __forceinline__ unsigned rne_bf16(float x) {
    unsigned u = __float_as_uint(x);
    return (u + 0x7fffu + ((u >> 16) & 1u)) >> 16;
}

// ---------------- setup: spectral norm + zero cnt/fill/deg0/gtotal
__global__ __launch_bounds__(256) void k_setup(const float* __restrict__ Wl_in, const float* __restrict__ Wr_in,
                                               float* __restrict__ Wl_out, float* __restrict__ Wr_out,
                                               int* __restrict__ cnt, int* __restrict__ fill,
                                               float* __restrict__ deg0, int* __restrict__ gtotal) {
    __shared__ float W[32 * 33];
    __shared__ float us[32], vs[32], tmp[32];
    __shared__ float scal;
    int t = threadIdx.x;
    if (blockIdx.x < 2) {
        int l = blockIdx.x;
        for (int i = t; i < 1024; i += 256) W[(i >> 5) * 33 + (i & 31)] = Wr_in[l * 1024 + i];
        if (t < 32) us[t] = 0.17677669529663688f;
        __syncthreads();
        for (int it = 0; it < 20; ++it) {
            if (t < 32) { float a = 0; for (int r = 0; r < 32; ++r) a = fmaf(W[r * 33 + t], us[r], a); tmp[t] = a; }
            __syncthreads();
            if (t == 0) { float s = 0; for (int c = 0; c < 32; ++c) s += tmp[c] * tmp[c]; scal = 1.0f / (sqrtf(s) + 1e-12f); }
            __syncthreads();
            if (t < 32) vs[t] = tmp[t] * scal;
            __syncthreads();
            if (t < 32) { float a = 0; for (int c = 0; c < 32; ++c) a = fmaf(W[t * 33 + c], vs[c], a); tmp[t] = a; }
            __syncthreads();
            if (t == 0) { float s = 0; for (int r = 0; r < 32; ++r) s += tmp[r] * tmp[r]; scal = 1.0f / (sqrtf(s) + 1e-12f); }
            __syncthreads();
            if (t < 32) us[t] = tmp[t] * scal;
            __syncthreads();
        }
        if (t < 32) { float a = 0; for (int r = 0; r < 32; ++r) a = fmaf(W[r * 33 + t], us[r], a); tmp[t] = a; }
        __syncthreads();
        if (t == 0) {
            float s = 0; for (int c = 0; c < 32; ++c) s += tmp[c] * tmp[c];
            scal = (sqrtf(s) + 1e-12f) / s;   // 1/sigma
        }
        __syncthreads();
        for (int i = t; i < 1024; i += 256) Wr_out[l * 1024 + i] = W[(i >> 5) * 33 + (i & 31)] * scal;
        if (t == 0) {
            float M[9];
            for (int i = 0; i < 9; ++i) M[i] = Wl_in[l * 9 + i];
            float u[3] = {0.5773502691896258f, 0.5773502691896258f, 0.5773502691896258f};
            float v[3], u2[3];
            for (int it = 0; it < 20; ++it) {
                float s = 0;
                for (int c = 0; c < 3; ++c) { v[c] = M[c] * u[0] + M[3 + c] * u[1] + M[6 + c] * u[2]; s += v[c] * v[c]; }
                float inv = 1.0f / (sqrtf(s) + 1e-12f);
                for (int c = 0; c < 3; ++c) v[c] *= inv;
                s = 0;
                for (int r = 0; r < 3; ++r) { u2[r] = M[r * 3] * v[0] + M[r * 3 + 1] * v[1] + M[r * 3 + 2] * v[2]; s += u2[r] * u2[r]; }
                inv = 1.0f / (sqrtf(s) + 1e-12f);
                for (int r = 0; r < 3; ++r) u[r] = u2[r] * inv;
            }
            float s = 0;
            for (int c = 0; c < 3; ++c) { v[c] = M[c] * u[0] + M[3 + c] * u[1] + M[6 + c] * u[2]; s += v[c] * v[c]; }
            float inv = (sqrtf(s) + 1e-12f) / s;
            for (int i = 0; i < 9; ++i) Wl_out[l * 9 + i] = M[i] * inv;
        }
    } else {
        int base = (blockIdx.x - 2) * 256 + t;
        int stride = (gridDim.x - 2) * 256;
        if (blockIdx.x == 2 && t == 0) *gtotal = 0;
        for (int i = base; i < NN; i += stride) { cnt[i] = 0; fill[i] = 0; deg0[i] = 0.0f; }
    }
}

// ---------------- MFMA GEMM: multi-tile grid-stride + N column-split (r11-proven)
template<int K, int N, int NH, bool ELU, bool HIST>
__global__ __launch_bounds__(256) void k_gemm(const float* __restrict__ X,
                                              const float* __restrict__ W,
                                              const float* __restrict__ bias,
                                              float* __restrict__ out,
                                              const int* __restrict__ row, int* __restrict__ cnt) {
    constexpr int KP = K + 8;
    constexpr int NT = NH / 16;
    constexpr int KS = K / 32;
    constexpr int NHALVES = N / NH;
    __shared__ __align__(16) unsigned short whi[NH * KP];
    __shared__ __align__(16) unsigned short wlo[NH * KP];
    int tid = threadIdx.x;
    if (HIST) {   // independent atomics first; latency hides behind GEMM
        for (int e = blockIdx.x * 256 + tid; e < E2; e += gridDim.x * 256)
            atomicAdd(&cnt[row[e]], 1);
    }
    const int ch = blockIdx.x % NHALVES;
    const int tstream = blockIdx.x / NHALVES;
    const int nstreams = gridDim.x / NHALVES;
    for (int i = tid; i < NH * K; i += 256) {
        float v = W[ch * NH * K + i];
        int r = i / K, c = i % K;
        unsigned h = rne_bf16(v);
        whi[r * KP + c] = (unsigned short)h;
        wlo[r * KP + c] = (unsigned short)rne_bf16(v - __uint_as_float(h << 16));
    }
    __syncthreads();
    int wave = tid >> 6, lane = tid & 63;
    int quad = lane >> 4, r16 = lane & 15;
    for (int t = tstream; t < NTILES; t += nstreams) {
        long m = (long)t * 64 + wave * 16 + r16;
        long mc = m < NN ? m : (NN - 1);
        const float* xrow = X + mc * K + quad * 8;
        short8 ah[KS], al[KS];
#pragma unroll
        for (int ks = 0; ks < KS; ++ks) {
            const float4* xp = (const float4*)(xrow + ks * 32);
            float4 p0 = xp[0], p1 = xp[1];
            float xv[8] = {p0.x, p0.y, p0.z, p0.w, p1.x, p1.y, p1.z, p1.w};
#pragma unroll
            for (int j = 0; j < 8; ++j) {
                unsigned h = rne_bf16(xv[j]);
                ah[ks][j] = (short)h;
                al[ks][j] = (short)rne_bf16(xv[j] - __uint_as_float(h << 16));
            }
        }
        long mbase = (long)t * 64 + wave * 16 + quad * 4;
#pragma unroll
        for (int tt = 0; tt < NT; ++tt) {
            f32x4 acc = (f32x4){0.f, 0.f, 0.f, 0.f};
#pragma unroll
            for (int ks = 0; ks < KS; ++ks) {
                int ro = (tt * 16 + r16) * KP + ks * 32 + quad * 8;
                short8 bh = *(const short8*)&whi[ro];
                short8 bl = *(const short8*)&wlo[ro];
                acc = __builtin_amdgcn_mfma_f32_16x16x32_bf16(ah[ks], bh, acc, 0, 0, 0);
                acc = __builtin_amdgcn_mfma_f32_16x16x32_bf16(al[ks], bh, acc, 0, 0, 0);
                acc = __builtin_amdgcn_mfma_f32_16x16x32_bf16(ah[ks], bl, acc, 0, 0, 0);
            }
            // C/D layout: col = lane&15, row = quad*4 + reg [m89-verified]
            int coln = ch * NH + tt * 16 + r16;
            float b = bias[coln];
#pragma unroll
            for (int rr = 0; rr < 4; ++rr) {
                long mm = mbase + rr;
                if (mm < NN) {
                    float v = acc[rr] + b;
                    if (ELU) v = eluf(v);
                    out[mm * N + coln] = v;
                }
            }
        }
    }
}

// ---------------- single-pass scan: local prefix + atomic grid offset -> absolute start
__global__ __launch_bounds__(256) void k_scan(const int* __restrict__ cnt, int* __restrict__ start,
                                              int* __restrict__ gtotal) {
    __shared__ int s[256];
    __shared__ int soff;
    int b = blockIdx.x, t = threadIdx.x;
    int i = b * 256 + t;
    int v = (i < NN) ? cnt[i] : 0;
    s[t] = v;
    __syncthreads();
    for (int off = 1; off < 256; off <<= 1) {
        int add = (t >= off) ? s[t - off] : 0;
        __syncthreads();
        s[t] += add;
        __syncthreads();
    }
    if (t == 255) soff = atomicAdd(gtotal, s[255]);   // chunk order nondeterministic; slots stay disjoint
    __syncthreads();
    if (i < NN) start[i] = s[t] - v + soff;
}

// ---------------- fused: blocks [0,NGROUPS) = y8 layer 0 ; [NGROUPS, +EB) = CSR fill
__global__ __launch_bounds__(256) void k_filly8(const float* __restrict__ xc,
                                                const float* __restrict__ Wl, const float* __restrict__ Wr,
                                                const float* __restrict__ Wsh, const float* __restrict__ Wwt,
                                                unsigned* __restrict__ yA, unsigned short* __restrict__ yB,
                                                float4* __restrict__ proj,
                                                const int* __restrict__ row, const int* __restrict__ start,
                                                int* __restrict__ fill, int* __restrict__ eslot) {
    int tid = threadIdx.x;
    if (blockIdx.x >= NGROUPS) {   // CSR fill branch
        int e = (blockIdx.x - NGROUPS) * 256 + tid;
        if (e < E2) {
            int u = row[e];
            eslot[e] = start[u] + atomicAdd(&fill[u], 1);
        }
        return;
    }
    __shared__ float wrs[32 * 33];
    __shared__ float wls[9];
    __shared__ float xcs[8][96];
    __shared__ float ws1[192], wt[192];
    int n0 = blockIdx.x * 8;
    for (int i = tid; i < 1024; i += 256) wrs[(i >> 5) * 33 + (i & 31)] = Wr[i];
    if (tid < 9) wls[tid] = Wl[tid];
    if (tid < 192) {
        ws1[tid] = Wsh[192 + tid];   // layer 0, row 1 of W_sheaf (only row surviving Cayley, D=2)
        wt[tid]  = Wwt[tid];
    }
    for (int i = tid; i < 192; i += 256) {
        int nd = i / 24, of = (i % 24) * 4;
        *(float4*)&xcs[nd][of] = *(const float4*)&xc[(n0 + nd) * 96 + of];
    }
    __syncthreads();
    int node = tid >> 5, c = tid & 31;
    int n = n0 + node;
    float a1 = 0, a2 = 0, a3 = 0, a4 = 0;
#pragma unroll
    for (int j = 0; j < 3; ++j) {
        int k = j * 32 + c;
        float xv = xcs[node][k];
        a1 = fmaf(xv, ws1[k], a1);
        a2 = fmaf(xv, ws1[96 + k], a2);
        a3 = fmaf(xv, wt[k], a3);
        a4 = fmaf(xv, wt[96 + k], a4);
    }
#pragma unroll
    for (int off = 16; off; off >>= 1) {
        a1 += __shfl_xor(a1, off);
        a2 += __shfl_xor(a2, off);
        a3 += __shfl_xor(a3, off);
        a4 += __shfl_xor(a4, off);
    }
    if (c == 0) proj[n] = make_float4(a1, a2, a3, a4);   // {aR, aC, wR, wC}
    {
        float t0 = 0, t1 = 0, t2 = 0;
        const float* wr = &wrs[c * 33];
        const float* xr = xcs[node];
#pragma unroll
        for (int h = 0; h < 32; ++h) {
            float w = wr[h];
            t0 = fmaf(xr[h], w, t0);
            t1 = fmaf(xr[32 + h], w, t1);
            t2 = fmaf(xr[64 + h], w, t2);
        }
        float o0 = wls[0] * t0 + wls[1] * t1 + wls[2] * t2;
        float o1 = wls[3] * t0 + wls[4] * t1 + wls[5] * t2;
        float o2 = wls[6] * t0 + wls[7] * t1 + wls[8] * t2;
        yA[n * 32 + c] = rne_bf16(o0) | (rne_bf16(o1) << 16);
        yB[n * 32 + c] = (unsigned short)rne_bf16(o2);
    }
}

// ---------------- per-edge coefficients, 8B packed meta + degree
__global__ __launch_bounds__(256) void k_coef(const int* __restrict__ row, const int* __restrict__ col,
                                              const int* __restrict__ eslot,
                                              const float4* __restrict__ proj,
                                              uint2* __restrict__ meta, float* __restrict__ deg) {
    int e = blockIdx.x * 256 + threadIdx.x;
    if (e >= E0) return;
    int u = row[e], v = col[e];
    float4 pu = proj[u], pv = proj[v];
    float a_e = ftanh(pu.x + pv.y);
    float a_r = ftanh(pv.x + pu.y);
    float wd_e = fsig(pu.z + pv.w);
    float wd_r = fsig(pv.z + pu.w);
    float w = wd_e * wd_r;
    float w2 = w * w;
    float ie = 1.0f / (1.0f + a_e * a_e), ir = 1.0f / (1.0f + a_r * a_r);
    float ce = (1.0f - a_e * a_e) * ie, se = 2.0f * a_e * ie;
    float cr = (1.0f - a_r * a_r) * ir, sr = 2.0f * a_r * ir;
    float C = ce * cr + se * sr;   // T_e = Q_e^T Q_rev ; T_rev = T_e^T -> (C,-S)
    float S = ce * sr - se * cr;
    unsigned cb = rne_bf16(C), sb = rne_bf16(S), wb = rne_bf16(w2);
    meta[eslot[e]]      = make_uint2(cb | (sb << 16), (unsigned)v | (wb << 16));
    meta[eslot[e + E0]] = make_uint2(cb | ((sb ^ 0x8000u) << 16), (unsigned)u | (wb << 16));
    atomicAdd(&deg[u], w2);
    atomicAdd(&deg[v], w2);
}

// ---------------- gather body (shared by both gather kernels), 4x-unrolled j-loop
__device__ __forceinline__ void gather_accum(int s0, int ec, int c,
                                             const uint2* __restrict__ meta,
                                             const float* __restrict__ deg, float du,
                                             const unsigned* __restrict__ yA,
                                             const unsigned short* __restrict__ yB,
                                             float& acc0, float& acc1, float& acc2) {
    for (int bs = 0; bs < ec; bs += 32) {
        int nb2 = min(32, ec - bs);
        float CC = 0, SS = 0, cnl = 0;
        int vj = 0;
        if (c < nb2) {
            uint2 mt = meta[s0 + bs + c];
            vj = (int)(mt.y & 0xffffu);
            float w2 = __uint_as_float(mt.y & 0xffff0000u);
            float Cv = __uint_as_float(mt.x << 16);
            float Sv = __uint_as_float(mt.x & 0xffff0000u);
            float dv = deg[vj];
            float dvi = dv > 0.0f ? rsqrtf(fmaxf(dv, 1e-30f)) : 0.0f;
            cnl = w2 * du * dvi;
            CC = cnl * Cv;
            SS = cnl * Sv;
        }
        int j4 = nb2 & ~3;
        int j = 0;
        for (; j < j4; j += 4) {
#pragma unroll
            for (int jj = 0; jj < 4; ++jj) {
                float Cj = __shfl(CC, j + jj, 32);
                float Sj = __shfl(SS, j + jj, 32);
                float cj = __shfl(cnl, j + jj, 32);
                int v = __shfl(vj, j + jj, 32);
                unsigned ua = yA[v * 32 + c];
                unsigned ub = (unsigned)yB[v * 32 + c];
                float y0 = __uint_as_float(ua << 16);
                float y1 = __uint_as_float(ua & 0xffff0000u);
                float y2 = __uint_as_float(ub << 16);
                acc0 = fmaf(Cj, y0, acc0);
                acc0 = fmaf(-Sj, y1, acc0);
                acc1 = fmaf(Sj, y0, acc1);
                acc1 = fmaf(Cj, y1, acc1);
                acc2 = fmaf(cj, y2, acc2);
            }
        }
        for (; j < nb2; ++j) {
            float Cj = __shfl(CC, j, 32);
            float Sj = __shfl(SS, j, 32);
            float cj = __shfl(cnl, j, 32);
            int v = __shfl(vj, j, 32);
            unsigned ua = yA[v * 32 + c];
            unsigned ub = (unsigned)yB[v * 32 + c];
            float y0 = __uint_as_float(ua << 16);
            float y1 = __uint_as_float(ua & 0xffff0000u);
            float y2 = __uint_as_float(ub << 16);
            acc0 = fmaf(Cj, y0, acc0);
            acc0 = fmaf(-Sj, y1, acc0);
            acc1 = fmaf(Sj, y0, acc1);
            acc1 = fmaf(Cj, y1, acc1);
            acc2 = fmaf(cj, y2, acc2);
        }
    }
}

// ---------------- gather layer 0 + residual + FUSED y8 layer 1 (ping-pong y/deg)
__global__ __launch_bounds__(256) void k_gatherY(const int* __restrict__ start,
                                                 const int* __restrict__ cnt,
                                                 const uint2* __restrict__ meta,
                                                 const float* __restrict__ deg0,
                                                 const unsigned* __restrict__ yA0,
                                                 const unsigned short* __restrict__ yB0,
                                                 const float* __restrict__ eps,
                                                 float* __restrict__ xc,
                                                 const float* __restrict__ Wl, const float* __restrict__ Wr,
                                                 const float* __restrict__ Wsh, const float* __restrict__ Wwt,
                                                 unsigned* __restrict__ yA1, unsigned short* __restrict__ yB1,
                                                 float4* __restrict__ proj, float* __restrict__ deg1) {
    __shared__ float wrs[32 * 33];
    __shared__ float wls[9];
    __shared__ float xcs[8][96];
    __shared__ float ws1[192], wt[192];
    int tid = threadIdx.x;
    for (int i = tid; i < 1024; i += 256) wrs[(i >> 5) * 33 + (i & 31)] = Wr[i];
    if (tid < 9) wls[tid] = Wl[tid];
    if (tid < 192) {
        ws1[tid] = Wsh[(1 * 3 + 1) * 192 + tid];   // layer 1 sheaf row
        wt[tid]  = Wwt[1 * 192 + tid];
    }
    int node = tid >> 5, c = tid & 31;
    int n = blockIdx.x * 8 + node;                 // NGROUPS*8 == NN: always in range
    int s0 = start[n], ec = cnt[n];
    float dn = deg0[n];
    float du = dn > 0.0f ? rsqrtf(fmaxf(dn, 1e-30f)) : 0.0f;
    float acc0 = 0, acc1 = 0, acc2 = 0;
    gather_accum(s0, ec, c, meta, deg0, du, yA0, yB0, acc0, acc1, acc2);
    float diag = dn > 0.0f ? 1.0f : 0.0f;
    unsigned ua = yA0[n * 32 + c];
    unsigned ub = (unsigned)yB0[n * 32 + c];
    float oy0 = __uint_as_float(ua << 16);
    float oy1 = __uint_as_float(ua & 0xffff0000u);
    float oy2 = __uint_as_float(ub << 16);
    float c0 = 1.0f + tanhf(eps[0]);
    float c1 = 1.0f + tanhf(eps[1]);
    float c2 = 1.0f + tanhf(eps[2]);
    int base = n * 96 + c;
    float nx0 = c0 * xc[base]      - eluf(diag * oy0 - acc0);
    float nx1 = c1 * xc[base + 32] - eluf(diag * oy1 - acc1);
    float nx2 = c2 * xc[base + 64] - eluf(diag * oy2 - acc2);
    xc[base] = nx0; xc[base + 32] = nx1; xc[base + 64] = nx2;
    if (c == 0) deg1[n] = 0.0f;                    // zero next layer's degree
    xcs[node][c] = nx0; xcs[node][32 + c] = nx1; xcs[node][64 + c] = nx2;
    __syncthreads();
    // ---- layer-1 projections (own channels in registers) ----
    float a1 = nx0 * ws1[c] + nx1 * ws1[32 + c] + nx2 * ws1[64 + c];
    float a2 = nx0 * ws1[96 + c] + nx1 * ws1[128 + c] + nx2 * ws1[160 + c];
    float a3 = nx0 * wt[c] + nx1 * wt[32 + c] + nx2 * wt[64 + c];
    float a4 = nx0 * wt[96 + c] + nx1 * wt[128 + c] + nx2 * wt[160 + c];
#pragma unroll
    for (int off = 16; off; off >>= 1) {
        a1 += __shfl_xor(a1, off);
        a2 += __shfl_xor(a2, off);
        a3 += __shfl_xor(a3, off);
        a4 += __shfl_xor(a4, off);
    }
    if (c == 0) proj[n] = make_float4(a1, a2, a3, a4);
    // ---- layer-1 y ----
    {
        float t0 = 0, t1 = 0, t2 = 0;
        const float* wr = &wrs[c * 33];
        const float* xr = xcs[node];
#pragma unroll
        for (int h = 0; h < 32; ++h) {
            float w = wr[h];
            t0 = fmaf(xr[h], w, t0);
            t1 = fmaf(xr[32 + h], w, t1);
            t2 = fmaf(xr[64 + h], w, t2);
        }
        float o0 = wls[0] * t0 + wls[1] * t1 + wls[2] * t2;
        float o1 = wls[3] * t0 + wls[4] * t1 + wls[5] * t2;
        float o2 = wls[6] * t0 + wls[7] * t1 + wls[8] * t2;
        yA1[n * 32 + c] = rne_bf16(o0) | (rne_bf16(o1) << 16);
        yB1[n * 32 + c] = (unsigned short)rne_bf16(o2);
    }
}

// ---------------- plain gather + residual (layer 1)
__global__ __launch_bounds__(256) void k_gather(const int* __restrict__ start,
                                                const int* __restrict__ cnt,
                                                const uint2* __restrict__ meta,
                                                const float* __restrict__ deg,
                                                const unsigned* __restrict__ yA,
                                                const unsigned short* __restrict__ yB,
                                                const float* __restrict__ eps,
                                                int layer, float* __restrict__ xc) {
    int tid = threadIdx.x;
    int node = tid >> 5, c = tid & 31;
    int n = blockIdx.x * 8 + node;
    if (n >= NN) return;
    int s0 = start[n], ec = cnt[n];
    float dn = deg[n];
    float du = dn > 0.0f ? rsqrtf(fmaxf(dn, 1e-30f)) : 0.0f;
    float acc0 = 0, acc1 = 0, acc2 = 0;
    gather_accum(s0, ec, c, meta, deg, du, yA, yB, acc0, acc1, acc2);
    float diag = dn > 0.0f ? 1.0f : 0.0f;
    unsigned ua = yA[n * 32 + c];
    unsigned ub = (unsigned)yB[n * 32 + c];
    float oy0 = __uint_as_float(ua << 16);
    float oy1 = __uint_as_float(ua & 0xffff0000u);
    float oy2 = __uint_as_float(ub << 16);
    float c0 = 1.0f + tanhf(eps[layer * 3 + 0]);
    float c1 = 1.0f + tanhf(eps[layer * 3 + 1]);
    float c2 = 1.0f + tanhf(eps[layer * 3 + 2]);
    int base = n * 96 + c;
    float z0 = eluf(diag * oy0 - acc0);
    float z1 = eluf(diag * oy1 - acc1);
    float z2 = eluf(diag * oy2 - acc2);
    xc[base]      = c0 * xc[base]      - z0;
    xc[base + 32] = c1 * xc[base + 32] - z1;
    xc[base + 64] = c2 * xc[base + 64] - z2;
}

extern "C" void kernel_launch(void* const* d_in, const int* in_sizes, int n_in,
                              void* d_out, int out_size, void* d_ws, size_t ws_size,
                              hipStream_t stream) {
    const float* x     = (const float*)d_in[0];
    const int*   ei    = (const int*)d_in[1];
    const float* W1    = (const float*)d_in[2];
    const float* b1    = (const float*)d_in[3];
    const float* W2    = (const float*)d_in[4];
    const float* b2    = (const float*)d_in[5];
    const float* Wl    = (const float*)d_in[6];
    const float* Wr    = (const float*)d_in[7];
    const float* eps   = (const float*)d_in[8];
    const float* Wsh   = (const float*)d_in[9];
    const float* Wwt   = (const float*)d_in[10];
    float* out = (float*)d_out;
    const int* row = ei;        // edge_index[0]
    const int* col = ei + E2;   // edge_index[1]

    char* pc = (char*)d_ws;
    float* xc     = (float*)pc;          pc += (size_t)NN * 96 * 4;
    uint2* meta   = (uint2*)pc;          pc += (size_t)E2 * 8;
    unsigned* yA0 = (unsigned*)pc;       pc += (size_t)NN * 32 * 4;
    unsigned* yA1 = (unsigned*)pc;       pc += (size_t)NN * 32 * 4;
    unsigned short* yB0 = (unsigned short*)pc; pc += (size_t)NN * 32 * 2;
    unsigned short* yB1 = (unsigned short*)pc; pc += (size_t)NN * 32 * 2;
    pc = (char*)(((size_t)pc + 15) & ~(size_t)15);
    float4* proj  = (float4*)pc;         pc += (size_t)NN * 16;
    float* deg0   = (float*)pc;          pc += (size_t)NN * 4;
    float* deg1   = (float*)pc;          pc += (size_t)NN * 4;
    float* Wl_n   = (float*)pc;          pc += 32 * 4;
    float* Wr_n   = (float*)pc;          pc += 2048 * 4;
    int* cnt      = (int*)pc;            pc += (size_t)NN * 4;
    int* start    = (int*)pc;            pc += (size_t)NN * 4;
    int* fill     = (int*)pc;            pc += (size_t)NN * 4;
    int* eslot    = (int*)pc;            pc += (size_t)E2 * 4;
    int* gtotal   = (int*)pc;            pc += 4;

    // 9 dispatches total
    k_setup<<<34, 256, 0, stream>>>(Wl, Wr, Wl_n, Wr_n, cnt, fill, deg0, gtotal);
    k_gemm<128, 96, 48, true, true><<<512, 256, 0, stream>>>(x, W1, b1, xc, row, cnt);
    k_scan<<<NCHUNK, 256, 0, stream>>>(cnt, start, gtotal);
    k_filly8<<<NGROUPS + EB, 256, 0, stream>>>(xc, Wl_n, Wr_n, Wsh, Wwt,
                                               yA0, yB0, proj, row, start, fill, eslot);
    k_coef<<<(E0 + 255) / 256, 256, 0, stream>>>(row, col, eslot, proj, meta, deg0);
    k_gatherY<<<NGROUPS, 256, 0, stream>>>(start, cnt, meta, deg0, yA0, yB0, eps, xc,
                                           Wl_n + 9, Wr_n + 1024, Wsh, Wwt, yA1, yB1, proj, deg1);
    k_coef<<<(E0 + 255) / 256, 256, 0, stream>>>(row, col, eslot, proj, meta, deg1);
    k_gather<<<NGROUPS, 256, 0, stream>>>(start, cnt, meta, deg1, yA1, yB1, eps, 1, xc);
    k_gemm<96, 32, 32, false, false><<<512, 256, 0, stream>>>(xc, W2, b2, out, nullptr, nullptr);
}